// Round 3
// baseline (504.621 us; speedup 1.0000x reference)
//
#include <hip/hip_runtime.h>
#include <stdint.h>

// KroneckerMarkerCovariance, n=128, C=32, m=64.
//   prep: rte[k][a][b] = 1/te[a][b][k];  V -> bf16 (Vh row-major, Vt transposed)
//   k1:   W[k*64+mm][i*128+j] = bf16( sum_c v[i][j][c][mm] * VC[c][k] )
//   k3:   per (k,mm): 4-GEMM chain (bf16 MFMA, V frags loaded from global L1/L2),
//         U[km][j*128+i] (bf16)
//   k5:   out[i][j][c][mm] = sum_k U[km][j*128+i] * VC[c][k]   (fp32)

typedef unsigned short ushort_t;
typedef __attribute__((ext_vector_type(8))) short short8;   // 8 bf16
typedef __attribute__((ext_vector_type(4))) float f32x4;
typedef __attribute__((ext_vector_type(2))) float f32x2;

__device__ __forceinline__ ushort_t f2bf(float f) {
  union { float f; uint32_t u; } v; v.f = f;
  uint32_t u = v.u;
  return (ushort_t)((u + 0x7fffu + ((u >> 16) & 1u)) >> 16);  // RNE
}
__device__ __forceinline__ uint32_t pk2(float a, float b) {
  return (uint32_t)f2bf(a) | ((uint32_t)f2bf(b) << 16);
}
__device__ __forceinline__ float bf_lo(uint32_t w) {
  union { uint32_t u; float f; } v; v.u = w << 16; return v.f;
}
__device__ __forceinline__ float bf_hi(uint32_t w) {
  union { uint32_t u; float f; } v; v.u = w & 0xffff0000u; return v.f;
}

// ---------------- prep ----------------
__global__ __launch_bounds__(256) void prep_kernel(
    const float* __restrict__ te, const float* __restrict__ Vg,
    float* __restrict__ rte, ushort_t* __restrict__ Vhg, ushort_t* __restrict__ Vtg) {
  int b = blockIdx.x, t = threadIdx.x;
  if (b < 256) {
    int id = b * 256 + t;
    int o0 = id * 8;                 // rte flat = k*16384 + a*128 + b
    int k = o0 >> 14, ab0 = o0 & 16383;
    float r[8];
    #pragma unroll
    for (int e = 0; e < 8; ++e) r[e] = 1.0f / te[(ab0 + e) * 32 + k];
    *(float4*)(rte + o0)     = make_float4(r[0], r[1], r[2], r[3]);
    *(float4*)(rte + o0 + 4) = make_float4(r[4], r[5], r[6], r[7]);
  } else {
    int base = (b - 256) * 4096 + t;
    #pragma unroll
    for (int e = 0; e < 16; ++e) {
      int idx = base + e * 256;      // 0..16383
      ushort_t us = f2bf(Vg[idx]);
      Vhg[idx] = us;                               // Vh[r][c] = V[r][c]
      Vtg[(idx & 127) * 128 + (idx >> 7)] = us;    // Vt[c][r] = V[r][c]
    }
  }
}

// ---------------- k1: marker rotate + transpose ----------------
// block: 32 consecutive ji (= i*128+j), 16-mm chunk; 256 threads, 4 blocks/CU.
__global__ __launch_bounds__(256, 4) void k1_rot_t(
    const float* __restrict__ v, const float* __restrict__ VC, ushort_t* __restrict__ W) {
  __shared__ ushort_t S[16640];   // phase A: Xs[jj][c*16+mmi] stride 520 (33280B)
                                  // phase B: Wt[512][32]               (32768B)
  __shared__ float VCs[1024];     // [c][k]
  int t = threadIdx.x, bid = blockIdx.x;
  int jc = bid >> 2, mt = bid & 3;
  int ji0 = jc * 32, mm0 = mt * 16;

  #pragma unroll
  for (int e = 0; e < 4; ++e) VCs[e * 256 + t] = VC[e * 256 + t];

  // stage v slab -> bf16 Xs
  #pragma unroll
  for (int e = 0; e < 4; ++e) {
    int q = e * 256 + t;             // 0..1023
    int jj = q >> 5, c = q & 31;
    const float* src = v + (size_t)(ji0 + jj) * 2048 + c * 64 + mm0;
    float4 f0 = *(const float4*)(src);
    float4 f1 = *(const float4*)(src + 4);
    float4 f2 = *(const float4*)(src + 8);
    float4 f3 = *(const float4*)(src + 12);
    uint4 lo = make_uint4(pk2(f0.x, f0.y), pk2(f0.z, f0.w), pk2(f1.x, f1.y), pk2(f1.z, f1.w));
    uint4 hi = make_uint4(pk2(f2.x, f2.y), pk2(f2.z, f2.w), pk2(f3.x, f3.y), pk2(f3.z, f3.w));
    ushort_t* dst = &S[jj * 520 + c * 16];
    *(uint4*)dst = lo;
    *(uint4*)(dst + 8) = hi;
  }
  __syncthreads();

  int jj = t & 31, kq = t >> 5;
  f32x2 acc2[4][8];
  #pragma unroll
  for (int e = 0; e < 4; ++e)
    #pragma unroll
    for (int q = 0; q < 8; ++q) acc2[e][q] = (f32x2){0.f, 0.f};

  for (int c = 0; c < 32; ++c) {
    const uint32_t* xp = (const uint32_t*)&S[jj * 520 + c * 16];
    uint4 wa = *(const uint4*)xp;
    uint4 wb = *(const uint4*)(xp + 4);
    uint32_t w[8] = {wa.x, wa.y, wa.z, wa.w, wb.x, wb.y, wb.z, wb.w};
    f32x2 vc2[4];
    #pragma unroll
    for (int e = 0; e < 4; ++e) {
      float s = VCs[c * 32 + kq * 4 + e];
      vc2[e] = (f32x2){s, s};
    }
    #pragma unroll
    for (int q = 0; q < 8; ++q) {
      f32x2 x2 = (f32x2){bf_lo(w[q]), bf_hi(w[q])};
      #pragma unroll
      for (int e = 0; e < 4; ++e) acc2[e][q] += vc2[e] * x2;
    }
  }
  __syncthreads();   // all Xs reads done; S becomes Wt

  #pragma unroll
  for (int e = 0; e < 4; ++e)
    #pragma unroll
    for (int q = 0; q < 8; ++q) {
      int row = (kq * 4 + e) * 16 + 2 * q;
      S[row * 32 + jj]       = f2bf(acc2[e][q].x);
      S[(row + 1) * 32 + jj] = f2bf(acc2[e][q].y);
    }
  __syncthreads();

  int part = t & 3, rq = t >> 2;
  #pragma unroll
  for (int e = 0; e < 8; ++e) {
    int row = e * 64 + rq;
    int k = row >> 4, mmi = row & 15;
    uint4 d = *(const uint4*)&S[row * 32 + part * 8];
    *(uint4*)(W + (size_t)(k * 64 + mm0 + mmi) * 16384 + ji0 + part * 8) = d;
  }
}

// ---------------- k3: per-(k,mm) 4-GEMM chain, V from global ----------------
__device__ __forceinline__ void gemmGA(const ushort_t* __restrict__ Vg,
                                       const ushort_t (*__restrict__ Bm)[136],
                                       int r0, int c0, int lr, int lk, f32x4 acc[2][4]) {
  #pragma unroll
  for (int fr = 0; fr < 2; ++fr)
    #pragma unroll
    for (int fc = 0; fc < 4; ++fc) acc[fr][fc] = (f32x4){0.f, 0.f, 0.f, 0.f};
  #pragma unroll
  for (int kb = 0; kb < 4; ++kb) {
    short8 a[2], b[4];
    #pragma unroll
    for (int fr = 0; fr < 2; ++fr)
      a[fr] = *(const short8*)(Vg + (r0 + fr * 16 + lr) * 128 + kb * 32 + lk);
    #pragma unroll
    for (int fc = 0; fc < 4; ++fc)
      b[fc] = *(const short8*)&Bm[c0 + fc * 16 + lr][kb * 32 + lk];
    #pragma unroll
    for (int fr = 0; fr < 2; ++fr)
      #pragma unroll
      for (int fc = 0; fc < 4; ++fc)
        acc[fr][fc] = __builtin_amdgcn_mfma_f32_16x16x32_bf16(a[fr], b[fc], acc[fr][fc], 0, 0, 0);
  }
}
__device__ __forceinline__ void gemmGB(const ushort_t (*__restrict__ Am)[136],
                                       const ushort_t* __restrict__ Vg,
                                       int r0, int c0, int lr, int lk, f32x4 acc[2][4]) {
  #pragma unroll
  for (int fr = 0; fr < 2; ++fr)
    #pragma unroll
    for (int fc = 0; fc < 4; ++fc) acc[fr][fc] = (f32x4){0.f, 0.f, 0.f, 0.f};
  #pragma unroll
  for (int kb = 0; kb < 4; ++kb) {
    short8 a[2], b[4];
    #pragma unroll
    for (int fr = 0; fr < 2; ++fr)
      a[fr] = *(const short8*)&Am[r0 + fr * 16 + lr][kb * 32 + lk];
    #pragma unroll
    for (int fc = 0; fc < 4; ++fc)
      b[fc] = *(const short8*)(Vg + (c0 + fc * 16 + lr) * 128 + kb * 32 + lk);
    #pragma unroll
    for (int fr = 0; fr < 2; ++fr)
      #pragma unroll
      for (int fc = 0; fc < 4; ++fc)
        acc[fr][fc] = __builtin_amdgcn_mfma_f32_16x16x32_bf16(a[fr], b[fc], acc[fr][fc], 0, 0, 0);
  }
}

__global__ __launch_bounds__(512, 6) void k3_chain(
    const ushort_t* __restrict__ W, const ushort_t* __restrict__ Vhg,
    const ushort_t* __restrict__ Vtg, const float* __restrict__ rte,
    ushort_t* __restrict__ U) {
  __shared__ ushort_t Ab[128][136];   // 34816B, 3 blocks/CU (VGPR-capped)
  int t = threadIdx.x;
  int blk = blockIdx.x;               // k*64 + mm
  int kk = blk >> 6;

  {
    const uint4* Wp = (const uint4*)W + (size_t)blk * 2048;
    #pragma unroll
    for (int e = 0; e < 4; ++e) {
      int idx = e * 512 + t;
      int row = idx >> 4, part = idx & 15;
      *(uint4*)&Ab[row][part * 8] = Wp[idx];
    }
  }
  __syncthreads();

  int wave = t >> 6, lane = t & 63;
  int r0 = (wave >> 1) * 32, c0 = (wave & 1) * 64;
  int lr = lane & 15;
  int lk = (lane >> 4) * 8;
  int rowreg = (lane >> 4) * 4;

  f32x4 acc[2][4];

  // G1: D1[a][i] = sum_j Vt[a][j] * Ab[i][j]
  gemmGA(Vtg, Ab, r0, c0, lr, lk, acc);
  __syncthreads();
  #pragma unroll
  for (int fr = 0; fr < 2; ++fr)
    #pragma unroll
    for (int fc = 0; fc < 4; ++fc)
      #pragma unroll
      for (int r = 0; r < 4; ++r)
        Ab[r0 + fr * 16 + rowreg + r][c0 + fc * 16 + lr] = f2bf(acc[fr][fc][r]);
  __syncthreads();

  // G2: D2[a][b] = sum_i D1[a][i] Vt[b][i], then ./E (E symmetric)
  gemmGB(Ab, Vtg, r0, c0, lr, lk, acc);
  #pragma unroll
  for (int fr = 0; fr < 2; ++fr)
    #pragma unroll
    for (int fc = 0; fc < 4; ++fc)
      #pragma unroll
      for (int r = 0; r < 4; ++r) {
        int a = r0 + fr * 16 + rowreg + r;
        int bcol = c0 + fc * 16 + lr;
        acc[fr][fc][r] *= rte[(size_t)kk * 16384 + a * 128 + bcol];
      }
  __syncthreads();
  // store transposed: Ab[b][a]
  #pragma unroll
  for (int fr = 0; fr < 2; ++fr)
    #pragma unroll
    for (int fc = 0; fc < 4; ++fc) {
      int bcol = c0 + fc * 16 + lr;
      int abase = r0 + fr * 16 + rowreg;
      uint32_t lo = (uint32_t)f2bf(acc[fr][fc][0]) | ((uint32_t)f2bf(acc[fr][fc][1]) << 16);
      uint32_t hi = (uint32_t)f2bf(acc[fr][fc][2]) | ((uint32_t)f2bf(acc[fr][fc][3]) << 16);
      *(uint2*)&Ab[bcol][abase] = make_uint2(lo, hi);
    }
  __syncthreads();

  // G3: D4[i][b] = sum_a Vh[i][a] * Ab[b][a]
  gemmGA(Vhg, Ab, r0, c0, lr, lk, acc);
  __syncthreads();
  #pragma unroll
  for (int fr = 0; fr < 2; ++fr)
    #pragma unroll
    for (int fc = 0; fc < 4; ++fc)
      #pragma unroll
      for (int r = 0; r < 4; ++r)
        Ab[r0 + fr * 16 + rowreg + r][c0 + fc * 16 + lr] = f2bf(acc[fr][fc][r]);
  __syncthreads();

  // G4: D5[i][j] = sum_b D4[i][b] Vh[j][b]; direct bf16 store to U
  gemmGB(Ab, Vhg, r0, c0, lr, lk, acc);
  ushort_t* Ub = U + (size_t)blk * 16384;
  #pragma unroll
  for (int fr = 0; fr < 2; ++fr)
    #pragma unroll
    for (int fc = 0; fc < 4; ++fc)
      #pragma unroll
      for (int r = 0; r < 4; ++r)
        Ub[(r0 + fr * 16 + rowreg + r) * 128 + (c0 + fc * 16 + lr)] = f2bf(acc[fr][fc][r]);
}

// ---------------- k5: un-transpose + marker un-rotate ----------------
// block: 32 consecutive ji' (= j*128+i), 16-mm chunk; 256 threads, 4 blocks/CU.
__global__ __launch_bounds__(256, 4) void k5_unrot_t(
    const ushort_t* __restrict__ U, const float* __restrict__ VC, float* __restrict__ out) {
  __shared__ ushort_t Us[512 * 34];   // [k*16+mmi][jj], row stride 68B  (34816B)
  __shared__ float VCs[1024];         // [c][k]
  int t = threadIdx.x, bid = blockIdx.x;
  int jc = bid >> 2, mt = bid & 3;
  int jip0 = jc * 32, mm0 = mt * 16;

  #pragma unroll
  for (int e = 0; e < 4; ++e) VCs[e * 256 + t] = VC[e * 256 + t];

  #pragma unroll
  for (int e = 0; e < 2; ++e) {
    int row = e * 256 + t;            // k*16 + mmi
    int k = row >> 4, mmi = row & 15;
    const uint4* src = (const uint4*)(U + (size_t)(k * 64 + mm0 + mmi) * 16384 + jip0);
    uint4 d0 = src[0], d1 = src[1], d2 = src[2], d3 = src[3];
    uint32_t* dst = (uint32_t*)&Us[row * 34];   // 4B-aligned, bank-bijective (17 mod 32)
    dst[0] = d0.x;  dst[1] = d0.y;  dst[2]  = d0.z;  dst[3]  = d0.w;
    dst[4] = d1.x;  dst[5] = d1.y;  dst[6]  = d1.z;  dst[7]  = d1.w;
    dst[8] = d2.x;  dst[9] = d2.y;  dst[10] = d2.z;  dst[11] = d2.w;
    dst[12] = d3.x; dst[13] = d3.y; dst[14] = d3.z;  dst[15] = d3.w;
  }
  __syncthreads();

  int jj2 = t & 15, cq = t >> 4;      // thread: jj = 2*jj2 + {0,1}, c = cq*2 + {0,1}
  f32x2 acc2[2][16];                  // [c'][mm], f32x2 = (jj even, jj odd)
  #pragma unroll
  for (int e = 0; e < 2; ++e)
    #pragma unroll
    for (int q = 0; q < 16; ++q) acc2[e][q] = (f32x2){0.f, 0.f};

  for (int k = 0; k < 32; ++k) {
    float s0 = VCs[(cq * 2 + 0) * 32 + k];
    float s1 = VCs[(cq * 2 + 1) * 32 + k];
    f32x2 v0 = (f32x2){s0, s0}, v1 = (f32x2){s1, s1};
    #pragma unroll
    for (int q = 0; q < 16; ++q) {
      uint32_t w = *(const uint32_t*)&Us[(k * 16 + q) * 34 + 2 * jj2];
      f32x2 y2 = (f32x2){bf_lo(w), bf_hi(w)};
      acc2[0][q] += v0 * y2;
      acc2[1][q] += v1 * y2;
    }
  }

  // ji' = j*128+i  ->  i = (jc&3)*32 + jj, j = jc>>2
  int i = ((jc & 3) << 5) + 2 * jj2;
  int j = jc >> 2;
  #pragma unroll
  for (int cc = 0; cc < 2; ++cc) {
    int c = cq * 2 + cc;
    float* o0 = out + (((size_t)i * 128 + j) * 32 + c) * 64 + mm0;
    float* o1 = o0 + (size_t)128 * 32 * 64;   // i+1
    #pragma unroll
    for (int z = 0; z < 4; ++z) {
      *(float4*)(o0 + z * 4) = make_float4(acc2[cc][z * 4 + 0].x, acc2[cc][z * 4 + 1].x,
                                           acc2[cc][z * 4 + 2].x, acc2[cc][z * 4 + 3].x);
      *(float4*)(o1 + z * 4) = make_float4(acc2[cc][z * 4 + 0].y, acc2[cc][z * 4 + 1].y,
                                           acc2[cc][z * 4 + 2].y, acc2[cc][z * 4 + 3].y);
    }
  }
}

extern "C" void kernel_launch(void* const* d_in, const int* in_sizes, int n_in,
                              void* d_out, int out_size, void* d_ws, size_t ws_size,
                              hipStream_t stream) {
  (void)in_sizes; (void)n_in; (void)out_size; (void)ws_size;
  const float* v  = (const float*)d_in[0];
  const float* VC = (const float*)d_in[1];
  const float* Vg = (const float*)d_in[2];
  const float* te = (const float*)d_in[3];
  float* out = (float*)d_out;

  char* ws = (char*)d_ws;
  ushort_t* W   = (ushort_t*)(ws);                      // 67,108,864 B
  ushort_t* U   = (ushort_t*)(ws + 67108864);           // 67,108,864 B
  float*    rte = (float*)   (ws + 134217728);          //  2,097,152 B
  ushort_t* Vhg = (ushort_t*)(ws + 136314880);          //     32,768 B
  ushort_t* Vtg = (ushort_t*)(ws + 136347648);          //     32,768 B

  prep_kernel<<<260, 256, 0, stream>>>(te, Vg, rte, Vhg, Vtg);
  k1_rot_t<<<2048, 256, 0, stream>>>(v, VC, W);
  k3_chain<<<2048, 512, 0, stream>>>(W, Vhg, Vtg, rte, U);
  k5_unrot_t<<<2048, 256, 0, stream>>>(U, VC, out);
}

// Round 4
// 431.229 us; speedup vs baseline: 1.1702x; 1.1702x over previous
//
#include <hip/hip_runtime.h>
#include <stdint.h>

// KroneckerMarkerCovariance, n=128, C=32, m=64.
//   prep: rte[k][a][b] = 1/te[a][b][k] (LDS-transposed, coalesced);  V -> bf16 (Vh, Vt)
//   k1:   W[k*64+mm][i*128+j] = bf16( sum_c v[i][j][c][mm] * VC[c][k] )  via MFMA
//         (batched 32x32x32 GEMM per mm-slice: D[k][jj] = VCt[k][c] * Xt[jj][c])
//   k3:   per (k,mm): 4-GEMM chain  V ((V^T B V)./E) V^T  in bf16 MFMA (LDS V),
//         U[km][j*128+i] bf16   [R2-verified structure]
//   k5:   out[i][j][c][mm] = sum_k U[km][j*128+i] * VC[c][k]   (fp32, VALU)

typedef unsigned short ushort_t;
typedef __attribute__((ext_vector_type(8))) short short8;   // 8 bf16
typedef __attribute__((ext_vector_type(4))) float f32x4;
typedef __attribute__((ext_vector_type(2))) float f32x2;

__device__ __forceinline__ ushort_t f2bf(float f) {
  union { float f; uint32_t u; } v; v.f = f;
  uint32_t u = v.u;
  return (ushort_t)((u + 0x7fffu + ((u >> 16) & 1u)) >> 16);  // RNE
}
__device__ __forceinline__ float bf_lo(uint32_t w) {
  union { uint32_t u; float f; } v; v.u = w << 16; return v.f;
}
__device__ __forceinline__ float bf_hi(uint32_t w) {
  union { uint32_t u; float f; } v; v.u = w & 0xffff0000u; return v.f;
}
__device__ __forceinline__ short8 lds8(const ushort_t* p) {
  union { short8 v; uint2 u[2]; } r;
  r.u[0] = *(const uint2*)p;
  r.u[1] = *(const uint2*)(p + 4);
  return r.v;
}

// ---------------- prep ----------------
__global__ __launch_bounds__(256) void prep_kernel(
    const float* __restrict__ te, const float* __restrict__ Vg,
    float* __restrict__ rte, ushort_t* __restrict__ Vhg, ushort_t* __restrict__ Vtg) {
  __shared__ float T[128 * 33];
  int b = blockIdx.x, t = threadIdx.x;
  if (b < 128) {
    // te[ab][k], ab = b*128..+128 -> rte[k][ab] = 1/te
    int base = b * 4096;
    #pragma unroll
    for (int e = 0; e < 16; ++e) {
      int idx = e * 256 + t;                       // 0..4095, coalesced
      T[(idx >> 5) * 33 + (idx & 31)] = te[base + idx];
    }
    __syncthreads();
    int k = t >> 3, part = t & 7;
    float r[16];
    #pragma unroll
    for (int s = 0; s < 16; ++s) r[s] = 1.0f / T[(part * 16 + s) * 33 + k];
    float* dst = rte + (size_t)k * 16384 + b * 128 + part * 16;
    *(float4*)(dst)      = make_float4(r[0],  r[1],  r[2],  r[3]);
    *(float4*)(dst + 4)  = make_float4(r[4],  r[5],  r[6],  r[7]);
    *(float4*)(dst + 8)  = make_float4(r[8],  r[9],  r[10], r[11]);
    *(float4*)(dst + 12) = make_float4(r[12], r[13], r[14], r[15]);
  } else {
    int base = (b - 128) * 4096 + t;
    #pragma unroll
    for (int e = 0; e < 16; ++e) {
      int idx = base + e * 256;                    // 0..16383
      ushort_t us = f2bf(Vg[idx]);
      Vhg[idx] = us;                               // Vh[r][c] = V[r][c]
      Vtg[(idx & 127) * 128 + (idx >> 7)] = us;    // Vt[c][r] = V[r][c]
    }
  }
}

// ---------------- k1: marker rotate + transpose via MFMA ----------------
// Block: 32 ji x 16 mm. 256 threads (4 waves, 4 mmi each).
// LDS u16 indices (all strides 8B-aligned for b64 reads):
//   Xs(mmi,jj,c) = mmi*1160 + jj*36 + c          [16][32][36]+pad   37120 B
//   VCt(k,c)     = 18560 + k*36 + c              [32][36]            2304 B
//   Wt(mmi,k,jj) = 19712 + mmi*1284 + k*40 + jj  [16][32][40]+pad   41088 B
#define K1_VCT 18560
#define K1_WT  19712
__global__ __launch_bounds__(256, 2) void k1_rot_t(
    const float* __restrict__ v, const float* __restrict__ VC, ushort_t* __restrict__ W) {
  __shared__ ushort_t S[40256];   // 80512 B total
  int t = threadIdx.x, bid = blockIdx.x;
  int jc = bid >> 2, mt = bid & 3;
  int ji0 = jc * 32, mm0 = mt * 16;

  // VCt[k][c] = bf16(VC[c*32+k])
  #pragma unroll
  for (int e = 0; e < 4; ++e) {
    int idx = e * 256 + t;                        // c*32+k
    S[K1_VCT + (idx & 31) * 36 + (idx >> 5)] = f2bf(VC[idx]);
  }
  // Xs[mmi][jj][c] = bf16(v[ji0+jj][c][mm0+mmi]); each thread owns one (jj,c) 64B row
  #pragma unroll
  for (int e = 0; e < 4; ++e) {
    int q = e * 256 + t;
    int jj = q >> 5, c = q & 31;
    const float* src = v + (size_t)(ji0 + jj) * 2048 + c * 64 + mm0;
    float4 f0 = *(const float4*)(src);
    float4 f1 = *(const float4*)(src + 4);
    float4 f2 = *(const float4*)(src + 8);
    float4 f3 = *(const float4*)(src + 12);
    float fv[16] = {f0.x, f0.y, f0.z, f0.w, f1.x, f1.y, f1.z, f1.w,
                    f2.x, f2.y, f2.z, f2.w, f3.x, f3.y, f3.z, f3.w};
    ushort_t* xp = &S[jj * 36 + c];
    #pragma unroll
    for (int mmi = 0; mmi < 16; ++mmi) xp[mmi * 1160] = f2bf(fv[mmi]);
  }
  __syncthreads();

  int lane = t & 63, wv = t >> 6;
  int lr = lane & 15, hi = lane >> 4;
  int lk = hi * 8, rowreg = hi * 4;

  // A-frags: VCt rows k (k = fr*16 + lr), elems c = lk..lk+7
  short8 a0 = lds8(&S[K1_VCT + lr * 36 + lk]);
  short8 a1 = lds8(&S[K1_VCT + (16 + lr) * 36 + lk]);
  #pragma unroll
  for (int p = 0; p < 4; ++p) {
    int mmi = wv * 4 + p;
    // B-frags: Xs[mmi] rows jj (col of D), elems c
    short8 b0 = lds8(&S[mmi * 1160 + lr * 36 + lk]);
    short8 b1 = lds8(&S[mmi * 1160 + (16 + lr) * 36 + lk]);
    f32x4 acc00 = {0.f,0.f,0.f,0.f}, acc01 = {0.f,0.f,0.f,0.f};
    f32x4 acc10 = {0.f,0.f,0.f,0.f}, acc11 = {0.f,0.f,0.f,0.f};
    acc00 = __builtin_amdgcn_mfma_f32_16x16x32_bf16(a0, b0, acc00, 0, 0, 0);
    acc01 = __builtin_amdgcn_mfma_f32_16x16x32_bf16(a0, b1, acc01, 0, 0, 0);
    acc10 = __builtin_amdgcn_mfma_f32_16x16x32_bf16(a1, b0, acc10, 0, 0, 0);
    acc11 = __builtin_amdgcn_mfma_f32_16x16x32_bf16(a1, b1, acc11, 0, 0, 0);
    // D[k][jj]: row k = fr*16 + rowreg + r, col jj = fc*16 + lr
    ushort_t* wp = &S[K1_WT + mmi * 1284];
    #pragma unroll
    for (int r = 0; r < 4; ++r) {
      wp[(rowreg + r) * 40 + lr]            = f2bf(acc00[r]);
      wp[(rowreg + r) * 40 + 16 + lr]       = f2bf(acc01[r]);
      wp[(16 + rowreg + r) * 40 + lr]       = f2bf(acc10[r]);
      wp[(16 + rowreg + r) * 40 + 16 + lr]  = f2bf(acc11[r]);
    }
  }
  __syncthreads();

  // out: 512 rows (k*64+mm0+mmi), 64 B each = 4 x 16B parts (full sectors)
  int part = t & 3, rq = t >> 2;
  #pragma unroll
  for (int e = 0; e < 8; ++e) {
    int rowid = e * 64 + rq;               // k*16 + mmi
    int k = rowid >> 4, mmi = rowid & 15;
    const ushort_t* p = &S[K1_WT + mmi * 1284 + k * 40 + part * 8];
    uint2 d0 = *(const uint2*)p;
    uint2 d1 = *(const uint2*)(p + 4);
    *(uint4*)(W + (size_t)(k * 64 + mm0 + mmi) * 16384 + ji0 + part * 8) =
        make_uint4(d0.x, d0.y, d1.x, d1.y);
  }
}

// ---------------- k3: per-(k,mm) 4-GEMM chain (R2-verified structure) ----------------
__device__ __forceinline__ void gemm128(const ushort_t (*__restrict__ Am)[136],
                                        const ushort_t (*__restrict__ Bm)[136],
                                        int r0, int c0, int lr, int lk, f32x4 acc[2][4]) {
  #pragma unroll
  for (int fr = 0; fr < 2; ++fr)
    #pragma unroll
    for (int fc = 0; fc < 4; ++fc) acc[fr][fc] = (f32x4){0.f, 0.f, 0.f, 0.f};
  #pragma unroll
  for (int kb = 0; kb < 4; ++kb) {
    short8 a[2], b[4];
    #pragma unroll
    for (int fr = 0; fr < 2; ++fr)
      a[fr] = *(const short8*)&Am[r0 + fr * 16 + lr][kb * 32 + lk];
    #pragma unroll
    for (int fc = 0; fc < 4; ++fc)
      b[fc] = *(const short8*)&Bm[c0 + fc * 16 + lr][kb * 32 + lk];
    #pragma unroll
    for (int fr = 0; fr < 2; ++fr)
      #pragma unroll
      for (int fc = 0; fc < 4; ++fc)
        acc[fr][fc] = __builtin_amdgcn_mfma_f32_16x16x32_bf16(a[fr], b[fc], acc[fr][fc], 0, 0, 0);
  }
}

__global__ __launch_bounds__(512, 2) void k3_chain(
    const ushort_t* __restrict__ W, const ushort_t* __restrict__ Vhg,
    const ushort_t* __restrict__ Vtg, const float* __restrict__ rte,
    ushort_t* __restrict__ U) {
  __shared__ ushort_t Ab[128][136];
  __shared__ ushort_t Vb[128][136];
  int t = threadIdx.x;
  int blk = blockIdx.x;               // k*64 + mm
  int kk = blk >> 6;

  {
    const uint4* Wp = (const uint4*)W + (size_t)blk * 2048;
    const uint4* Vp = (const uint4*)Vtg;
    #pragma unroll
    for (int e = 0; e < 4; ++e) {
      int idx = e * 512 + t;
      int row = idx >> 4, part = idx & 15;
      *(uint4*)&Ab[row][part * 8] = Wp[idx];
      *(uint4*)&Vb[row][part * 8] = Vp[idx];
    }
  }
  __syncthreads();

  int wave = t >> 6, lane = t & 63;
  int r0 = (wave >> 1) * 32, c0 = (wave & 1) * 64;
  int lr = lane & 15;
  int lk = (lane >> 4) * 8;
  int rowreg = (lane >> 4) * 4;

  f32x4 acc[2][4];

  // G1: D1[a][i] = sum_j Vt[a][j] * Ab[i][j]
  gemm128(Vb, Ab, r0, c0, lr, lk, acc);
  __syncthreads();
  #pragma unroll
  for (int fr = 0; fr < 2; ++fr)
    #pragma unroll
    for (int fc = 0; fc < 4; ++fc)
      #pragma unroll
      for (int r = 0; r < 4; ++r)
        Ab[r0 + fr * 16 + rowreg + r][c0 + fc * 16 + lr] = f2bf(acc[fr][fc][r]);
  __syncthreads();

  // G2: D2[a][b] = sum_i D1[a][i] Vt[b][i], then ./E (E symmetric)
  gemm128(Ab, Vb, r0, c0, lr, lk, acc);
  #pragma unroll
  for (int fr = 0; fr < 2; ++fr)
    #pragma unroll
    for (int fc = 0; fc < 4; ++fc)
      #pragma unroll
      for (int r = 0; r < 4; ++r) {
        int a = r0 + fr * 16 + rowreg + r;
        int bcol = c0 + fc * 16 + lr;
        acc[fr][fc][r] *= rte[(size_t)kk * 16384 + a * 128 + bcol];
      }
  __syncthreads();
  // store transposed: Ab[b][a]; reload Vb = Vh
  #pragma unroll
  for (int fr = 0; fr < 2; ++fr)
    #pragma unroll
    for (int fc = 0; fc < 4; ++fc) {
      int bcol = c0 + fc * 16 + lr;
      int abase = r0 + fr * 16 + rowreg;
      uint32_t lo = (uint32_t)f2bf(acc[fr][fc][0]) | ((uint32_t)f2bf(acc[fr][fc][1]) << 16);
      uint32_t hi = (uint32_t)f2bf(acc[fr][fc][2]) | ((uint32_t)f2bf(acc[fr][fc][3]) << 16);
      *(uint2*)&Ab[bcol][abase] = make_uint2(lo, hi);
    }
  {
    const uint4* Vp = (const uint4*)Vhg;
    #pragma unroll
    for (int e = 0; e < 4; ++e) {
      int idx = e * 512 + t;
      int row = idx >> 4, part = idx & 15;
      *(uint4*)&Vb[row][part * 8] = Vp[idx];
    }
  }
  __syncthreads();

  // G3: D4[i][b] = sum_a Vh[i][a] * Ab[b][a]
  gemm128(Vb, Ab, r0, c0, lr, lk, acc);
  __syncthreads();
  #pragma unroll
  for (int fr = 0; fr < 2; ++fr)
    #pragma unroll
    for (int fc = 0; fc < 4; ++fc)
      #pragma unroll
      for (int r = 0; r < 4; ++r)
        Ab[r0 + fr * 16 + rowreg + r][c0 + fc * 16 + lr] = f2bf(acc[fr][fc][r]);
  __syncthreads();

  // G4: D5[i][j] = sum_b D4[i][b] Vh[j][b]
  gemm128(Ab, Vb, r0, c0, lr, lk, acc);
  __syncthreads();
  #pragma unroll
  for (int fr = 0; fr < 2; ++fr)
    #pragma unroll
    for (int fc = 0; fc < 4; ++fc)
      #pragma unroll
      for (int r = 0; r < 4; ++r)
        Ab[r0 + fr * 16 + rowreg + r][c0 + fc * 16 + lr] = f2bf(acc[fr][fc][r]);
  __syncthreads();

  // coalesced bf16 U write
  {
    ushort_t* Ub = U + (size_t)blk * 16384;
    #pragma unroll
    for (int e = 0; e < 4; ++e) {
      int idx = e * 512 + t;
      int row = idx >> 4, part = idx & 15;
      *(uint4*)(Ub + row * 128 + part * 8) = *(const uint4*)&Ab[row][part * 8];
    }
  }
}

// ---------------- k5: un-transpose + marker un-rotate (VALU, R3-verified) ----------------
__global__ __launch_bounds__(256, 4) void k5_unrot_t(
    const ushort_t* __restrict__ U, const float* __restrict__ VC, float* __restrict__ out) {
  __shared__ ushort_t Us[512 * 34];   // [k*16+mmi][jj], row stride 68B
  __shared__ float VCs[1024];         // [c][k]
  int t = threadIdx.x, bid = blockIdx.x;
  int jc = bid >> 2, mt = bid & 3;
  int jip0 = jc * 32, mm0 = mt * 16;

  #pragma unroll
  for (int e = 0; e < 4; ++e) VCs[e * 256 + t] = VC[e * 256 + t];

  #pragma unroll
  for (int e = 0; e < 2; ++e) {
    int row = e * 256 + t;            // k*16 + mmi
    int k = row >> 4, mmi = row & 15;
    const uint4* src = (const uint4*)(U + (size_t)(k * 64 + mm0 + mmi) * 16384 + jip0);
    uint4 d0 = src[0], d1 = src[1], d2 = src[2], d3 = src[3];
    uint32_t* dst = (uint32_t*)&Us[row * 34];
    dst[0] = d0.x;  dst[1] = d0.y;  dst[2]  = d0.z;  dst[3]  = d0.w;
    dst[4] = d1.x;  dst[5] = d1.y;  dst[6]  = d1.z;  dst[7]  = d1.w;
    dst[8] = d2.x;  dst[9] = d2.y;  dst[10] = d2.z;  dst[11] = d2.w;
    dst[12] = d3.x; dst[13] = d3.y; dst[14] = d3.z;  dst[15] = d3.w;
  }
  __syncthreads();

  int jj2 = t & 15, cq = t >> 4;      // jj = 2*jj2 + {0,1}, c = cq*2 + {0,1}
  f32x2 acc2[2][16];
  #pragma unroll
  for (int e = 0; e < 2; ++e)
    #pragma unroll
    for (int q = 0; q < 16; ++q) acc2[e][q] = (f32x2){0.f, 0.f};

  for (int k = 0; k < 32; ++k) {
    float s0 = VCs[(cq * 2 + 0) * 32 + k];
    float s1 = VCs[(cq * 2 + 1) * 32 + k];
    f32x2 v0 = (f32x2){s0, s0}, v1 = (f32x2){s1, s1};
    #pragma unroll
    for (int q = 0; q < 16; ++q) {
      uint32_t w = *(const uint32_t*)&Us[(k * 16 + q) * 34 + 2 * jj2];
      f32x2 y2 = (f32x2){bf_lo(w), bf_hi(w)};
      acc2[0][q] += v0 * y2;
      acc2[1][q] += v1 * y2;
    }
  }

  // ji' = j*128+i  ->  i = (jc&3)*32 + jj, j = jc>>2
  int i = ((jc & 3) << 5) + 2 * jj2;
  int j = jc >> 2;
  #pragma unroll
  for (int cc = 0; cc < 2; ++cc) {
    int c = cq * 2 + cc;
    float* o0 = out + (((size_t)i * 128 + j) * 32 + c) * 64 + mm0;
    float* o1 = o0 + (size_t)128 * 32 * 64;   // i+1
    #pragma unroll
    for (int z = 0; z < 4; ++z) {
      *(float4*)(o0 + z * 4) = make_float4(acc2[cc][z * 4 + 0].x, acc2[cc][z * 4 + 1].x,
                                           acc2[cc][z * 4 + 2].x, acc2[cc][z * 4 + 3].x);
      *(float4*)(o1 + z * 4) = make_float4(acc2[cc][z * 4 + 0].y, acc2[cc][z * 4 + 1].y,
                                           acc2[cc][z * 4 + 2].y, acc2[cc][z * 4 + 3].y);
    }
  }
}

extern "C" void kernel_launch(void* const* d_in, const int* in_sizes, int n_in,
                              void* d_out, int out_size, void* d_ws, size_t ws_size,
                              hipStream_t stream) {
  (void)in_sizes; (void)n_in; (void)out_size; (void)ws_size;
  const float* v  = (const float*)d_in[0];
  const float* VC = (const float*)d_in[1];
  const float* Vg = (const float*)d_in[2];
  const float* te = (const float*)d_in[3];
  float* out = (float*)d_out;

  char* ws = (char*)d_ws;
  ushort_t* W   = (ushort_t*)(ws);                      // 67,108,864 B
  ushort_t* U   = (ushort_t*)(ws + 67108864);           // 67,108,864 B
  float*    rte = (float*)   (ws + 134217728);          //  2,097,152 B
  ushort_t* Vhg = (ushort_t*)(ws + 136314880);          //     32,768 B
  ushort_t* Vtg = (ushort_t*)(ws + 136347648);          //     32,768 B

  prep_kernel<<<132, 256, 0, stream>>>(te, Vg, rte, Vhg, Vtg);
  k1_rot_t<<<2048, 256, 0, stream>>>(v, VC, W);
  k3_chain<<<2048, 512, 0, stream>>>(W, Vhg, Vtg, rte, U);
  k5_unrot_t<<<2048, 256, 0, stream>>>(U, VC, out);
}